// Round 6
// baseline (47.745 us; speedup 1.0000x reference)
//
#include <hip/hip_runtime.h>

#define OUT_F 11008
#define IN_F  4096
#define KSTEP 128              // k per step: lane*2, int2/float2 loads
#define NSTEP (IN_F / KSTEP)   // 32 steps

// Block = 256 threads = 4 waves = 2 row-groups x 2 batch-halves.
// Wave = 8 output rows x 4 batches x full K (batch-split, NO K-split):
//   - 2752 waves total -> all resident in one generation (no drain bubble)
//   - no cross-wave combine -> no LDS, no barrier
//   - the two batch-half waves of a group share the 128 KB weight panel via
//     same-CU L1/L2.
// Both x and w are double-buffered (named arrays, static indexing); per step
// issue order: x(t+1), w(t+1), FMA(t) -> every FMA consumes data issued a
// full step earlier; the in-order vmcnt wait never drains the prefetch.
// zero-point folded: out = s*(dot - zp*rowsum(x_b)) + bias, rowsum in-loop.
// NOTE: plain __launch_bounds__(256) — ",N" variants forced spills (R3).
__global__ __launch_bounds__(256) void qlinear_kernel(
        const float* __restrict__ in, const int* __restrict__ qw,
        const int* __restrict__ zp, const float* __restrict__ scale,
        const float* __restrict__ bias, float* __restrict__ out) {
    const int lane  = threadIdx.x & 63;
    const int wave  = threadIdx.x >> 6;            // 0..3
    const int bh    = wave & 1;                    // batch half: batches bh*4..bh*4+3
    const int group = blockIdx.x * 2 + (wave >> 1);
    const int row0  = group * 8;
    const int l2    = lane * 2;

    const int*   qp = qw + (size_t)row0 * IN_F + l2;
    const float* xp = in + (size_t)(bh * 4) * IN_F + l2;

    float acc[8][4];
    float asum[4];
    #pragma unroll
    for (int r = 0; r < 8; ++r)
        #pragma unroll
        for (int b = 0; b < 4; ++b) acc[r][b] = 0.f;
    #pragma unroll
    for (int b = 0; b < 4; ++b) asum[b] = 0.f;

    float2 xA[4], xB[4];   // named double buffers -> guaranteed static indexing
    int2   wA[8], wB[8];

#define PREF(XB_, WB_, OFF) do {                                              \
        const int off_ = (OFF);                                               \
        _Pragma("unroll")                                                     \
        for (int b = 0; b < 4; ++b)                                           \
            XB_[b] = *reinterpret_cast<const float2*>(xp + b * IN_F + off_);  \
        _Pragma("unroll")                                                     \
        for (int r = 0; r < 8; ++r)                                           \
            WB_[r] = *reinterpret_cast<const int2*>(qp + r * IN_F + off_);    \
    } while (0)

#define FMA8(XB_, WB_) do {                                                   \
        float f_[8][2];                                                       \
        _Pragma("unroll")                                                     \
        for (int r = 0; r < 8; ++r) {                                         \
            f_[r][0] = (float)WB_[r].x;                                       \
            f_[r][1] = (float)WB_[r].y;                                       \
        }                                                                     \
        _Pragma("unroll")                                                     \
        for (int b = 0; b < 4; ++b) {                                         \
            const float2 xv = XB_[b];                                         \
            asum[b] += xv.x + xv.y;                                           \
            _Pragma("unroll")                                                 \
            for (int r = 0; r < 8; ++r)                                       \
                acc[r][b] += f_[r][0] * xv.x + f_[r][1] * xv.y;               \
        }                                                                     \
    } while (0)

    // prologue: step 0 into A
    PREF(xA, wA, 0);

    // main loop: 15 iterations x 2 steps; prefetch(t+1) issued before FMA(t)
    #pragma unroll 1
    for (int j = 0; j < NSTEP / 2 - 1; ++j) {
        PREF(xB, wB, (2 * j + 1) * KSTEP); FMA8(xA, wA);
        PREF(xA, wA, (2 * j + 2) * KSTEP); FMA8(xB, wB);
    }
    // peeled tail: steps 30,31
    PREF(xB, wB, (NSTEP - 1) * KSTEP); FMA8(xA, wA);
    FMA8(xB, wB);

#undef PREF
#undef FMA8

    // --- cross-lane reduce of 32 accumulators (register-halving tree):
    // after 5 levels + xor32, lane l (l<32) holds full sum of value index l,
    // where index = r*4 + b.
    float v[32];
    #pragma unroll
    for (int r = 0; r < 8; ++r)
        #pragma unroll
        for (int b = 0; b < 4; ++b) v[r * 4 + b] = acc[r][b];

    #pragma unroll
    for (int k = 0; k < 5; ++k) {
        const bool hi = (lane >> k) & 1;
        const int  nn = 32 >> k;
        #pragma unroll
        for (int i = 0; i < 32; ++i) {
            if (i < nn / 2) {
                float keep = hi ? v[2 * i + 1] : v[2 * i];
                float send = hi ? v[2 * i]     : v[2 * i + 1];
                v[i] = keep + __shfl_xor(send, 1 << k);
            }
        }
    }
    const float total = v[0] + __shfl_xor(v[0], 32);

    // --- reduce 4 row-sum accumulators -> rowsum of batch (lane&3)
    float s4[4];
    #pragma unroll
    for (int b = 0; b < 4; ++b) s4[b] = asum[b];
    #pragma unroll
    for (int k = 0; k < 2; ++k) {
        const bool hi = (lane >> k) & 1;
        const int  nn = 4 >> k;
        #pragma unroll
        for (int i = 0; i < 4; ++i) {
            if (i < nn / 2) {
                float keep = hi ? s4[2 * i + 1] : s4[2 * i];
                float send = hi ? s4[2 * i]     : s4[2 * i + 1];
                s4[i] = keep + __shfl_xor(send, 1 << k);
            }
        }
    }
    float S = s4[0];
    S += __shfl_xor(S, 4);
    S += __shfl_xor(S, 8);
    S += __shfl_xor(S, 16);
    S += __shfl_xor(S, 32);   // full rowsum of batch (lane&3) in this half

    if (lane < 32) {
        const int r  = lane >> 2;          // 0..7
        const int b  = lane & 3;           // 0..3
        const int o  = row0 + r;
        const int bg = bh * 4 + b;
        out[(size_t)bg * OUT_F + o] =
            scale[o] * (total - (float)zp[o] * S) + bias[o];
    }
}

extern "C" void kernel_launch(void* const* d_in, const int* in_sizes, int n_in,
                              void* d_out, int out_size, void* d_ws, size_t ws_size,
                              hipStream_t stream) {
    const float* in    = (const float*)d_in[0];
    const int*   qw    = (const int*)  d_in[1];
    const int*   zp    = (const int*)  d_in[2];
    const float* scale = (const float*)d_in[3];
    const float* bias  = (const float*)d_in[4];
    float*       out   = (float*)d_out;

    const int blocks = OUT_F / 16;   // 688 blocks: 2 groups x 2 batch-halves
    qlinear_kernel<<<blocks, 256, 0, stream>>>(in, qw, zp, scale, bias, out);
}